// Round 5
// baseline (332.677 us; speedup 1.0000x reference)
//
#include <hip/hip_runtime.h>
#include <hip/hip_bf16.h>

// Dynamic conv2d: B=16, C_in=64, H=W=128, C_out=64, K=5, ks=3, pad=1.
// R5: fused rolling-row conv. Fixes vs R4: loads issued at step START
// (post-barrier) with a full step of latency cover; output rows written
// rolling (at each wave's idle step) instead of a bursty epilogue.

typedef __attribute__((ext_vector_type(8))) __bf16 bf16x8;
typedef __attribute__((ext_vector_type(16))) float f32x16;
typedef __attribute__((ext_vector_type(2))) unsigned int u32x2;
typedef __attribute__((ext_vector_type(4))) unsigned int u32x4;

#define NB 16
#define CI 64
#define CO 64
#define HH 128
#define WW 128
#define KBANK 5
#define KDIM 576              // CI*9, k = tap*64 + ci
#define PITCH 72              // shorts per pixel (64 data + 8 pad = 144B, 16B-aligned)
#define BUFS (130 * PITCH)    // shorts per row buffer

__device__ __forceinline__ unsigned short f2bfu(float f) {
    __hip_bfloat16 h = __float2bfloat16(f);
    unsigned short s;
    __builtin_memcpy(&s, &h, 2);
    return s;
}

// ---------------- kernel 1: aggregate weights + bias ----------------
__global__ void prep_kernel(const float* __restrict__ weights,
                            const float* __restrict__ Wbank,
                            const float* __restrict__ bbank,
                            short* __restrict__ aggw,
                            float* __restrict__ aggb) {
    int idx = blockIdx.x * 256 + threadIdx.x;          // < 16*64*576
    int b  = idx / (CO * KDIM);
    int r  = idx - b * (CO * KDIM);
    int co = r / KDIM;
    int k  = r - co * KDIM;
    int tap = k >> 6;
    int ci  = k & 63;
    float s = 0.f;
#pragma unroll
    for (int kk = 0; kk < KBANK; ++kk)
        s += weights[b * KBANK + kk] * Wbank[((kk * CO + co) * CI + ci) * 9 + tap];
    aggw[idx] = (short)f2bfu(s);
    if (k == 0) {
        float sb = 0.f;
#pragma unroll
        for (int kk = 0; kk < KBANK; ++kk)
            sb += weights[b * KBANK + kk] * bbank[kk * CO + co];
        aggb[b * CO + co] = sb;
    }
}

// ---------------- kernel 2: fused rolling conv ----------------
__device__ __forceinline__ void load16(const float* __restrict__ xb, int r,
                                       int sw, int scg, float pv[16]) {
#pragma unroll
    for (int rr = 0; rr < 4; ++rr) {
        int ci0 = (rr * 4 + scg) * 4;
#pragma unroll
        for (int k = 0; k < 4; ++k)
            pv[rr * 4 + k] = xb[((size_t)(ci0 + k) * HH + r) * WW + sw];
    }
}

__device__ __forceinline__ void write16(short* __restrict__ nb, int sw, int scg,
                                        const float pv[16]) {
#pragma unroll
    for (int rr = 0; rr < 4; ++rr) {
        int ci0 = (rr * 4 + scg) * 4;
        unsigned int u0 = (unsigned)f2bfu(pv[rr * 4 + 0]) | ((unsigned)f2bfu(pv[rr * 4 + 1]) << 16);
        unsigned int u1 = (unsigned)f2bfu(pv[rr * 4 + 2]) | ((unsigned)f2bfu(pv[rr * 4 + 3]) << 16);
        *(u32x2*)&nb[(sw + 1) * PITCH + ci0] = u32x2{u0, u1};
    }
}

__global__ __launch_bounds__(512, 4) void conv_kernel(const float* __restrict__ x,
                                                      const short* __restrict__ aggw,
                                                      const float* __restrict__ aggb,
                                                      float* __restrict__ out) {
    __shared__ short ring[3 * BUFS];                   // 56,160 B

    const int t = threadIdx.x;
    int lin = blockIdx.y * 32 + blockIdx.x;            // 0..511
    lin = ((lin & 7) << 6) | (lin >> 3);               // bijective XCD swizzle
    const int hq = lin & 31;
    const int b  = lin >> 5;
    const int h0 = hq * 4;

    const int l    = t & 63;
    const int wv   = t >> 6;       // 0..7
    const int lm   = l & 31;
    const int g    = l >> 5;
    const int rl   = wv >> 1;      // output row 0..3 within block
    const int half = wv & 1;       // pix half

    const int sw  = t & 127;       // staging: w
    const int scg = t >> 7;        // staging: ci group 0..3

    const float* xb = x + (size_t)b * CI * HH * WW;
    const short* Aw = aggw + ((size_t)b * CO + lm) * KDIM;

    // zero halo pixels (pix 0 and 129) of all 3 buffers
    if (t < 48) {
        int bi = t >> 4, c = t & 15;
        int pix = (c >> 3) * 129, ch = c & 7;
        *(u32x4*)&ring[bi * BUFS + pix * PITCH + ch * 8] = u32x4{0u, 0u, 0u, 0u};
    }

    float pv[16];
    // prologue: stage row h0-1 into buf 0; then issue loads for row h0
    if (h0 >= 1) {
        load16(xb, h0 - 1, sw, scg, pv);
        write16(&ring[0], sw, scg, pv);                // implicit vmcnt wait
    }
    asm volatile("s_waitcnt lgkmcnt(0)" ::: "memory"); // pv WAR-safe after drain
    load16(xb, h0, sw, scg, pv);                       // covers during barrier+step0
    __builtin_amdgcn_s_barrier();
    __builtin_amdgcn_sched_barrier(0);

    f32x16 acc[2][2];
#pragma unroll
    for (int m = 0; m < 2; ++m)
#pragma unroll
        for (int n = 0; n < 2; ++n)
            acc[m][n] = (f32x16)0.0f;

#pragma unroll
    for (int s = 0; s < 6; ++s) {
        const int r  = h0 - 1 + s;                     // input row consumed
        const int dy = s - rl;
        const bool active = (dy >= 0) && (dy <= 2) && ((unsigned)r < 128u);
        const short* cb = &ring[(s % 3) * BUFS];

        // rolling output write: wave rl finished its row at end of step rl+2
        if (s >= 3 && rl == s - 3) {
            const int hrow = h0 + rl;
#pragma unroll
            for (int m = 0; m < 2; ++m)
#pragma unroll
                for (int n = 0; n < 2; ++n) {
                    const int wc = half * 64 + n * 32 + lm;
#pragma unroll
                    for (int rg = 0; rg < 16; ++rg) {
                        int co = m * 32 + (rg & 3) + 8 * (rg >> 2) + 4 * g;
                        out[(((size_t)b * CO + co) * HH + hrow) * WW + wc] =
                            acc[m][n][rg] + aggb[b * CO + co];
                    }
                }
        }

        if (active) {
            const int tb = dy * 3;
            __builtin_amdgcn_s_setprio(1);
#pragma unroll
            for (int dx = 0; dx < 3; ++dx) {
                const int tap = tb + dx;
#pragma unroll
                for (int q = 0; q < 4; ++q) {
                    bf16x8 a0 = *(const bf16x8*)(Aw + 0 * 32 * KDIM + tap * 64 + q * 16 + g * 8);
                    bf16x8 a1 = *(const bf16x8*)(Aw + 1 * 32 * KDIM + tap * 64 + q * 16 + g * 8);
                    const int p0 = half * 64 + lm + dx;
                    bf16x8 b0 = *(const bf16x8*)&cb[p0 * PITCH + (q * 2 + g) * 8];
                    bf16x8 b1 = *(const bf16x8*)&cb[(p0 + 32) * PITCH + (q * 2 + g) * 8];
                    acc[0][0] = __builtin_amdgcn_mfma_f32_32x32x16_bf16(a0, b0, acc[0][0], 0, 0, 0);
                    acc[0][1] = __builtin_amdgcn_mfma_f32_32x32x16_bf16(a0, b1, acc[0][1], 0, 0, 0);
                    acc[1][0] = __builtin_amdgcn_mfma_f32_32x32x16_bf16(a1, b0, acc[1][0], 0, 0, 0);
                    acc[1][1] = __builtin_amdgcn_mfma_f32_32x32x16_bf16(a1, b1, acc[1][1], 0, 0, 0);
                }
            }
            __builtin_amdgcn_s_setprio(0);
        }

        // stage row h0+s (loaded one step ago — full step of latency cover)
        if (s < 5 && h0 + s < 128)
            write16(&ring[((s + 1) % 3) * BUFS], sw, scg, pv);

        asm volatile("s_waitcnt lgkmcnt(0)" ::: "memory");
        __builtin_amdgcn_s_barrier();
        __builtin_amdgcn_sched_barrier(0);

        // issue next row's loads at step START (post-barrier): full-step cover
        if (s < 4 && h0 + s + 1 < 128)
            load16(xb, h0 + s + 1, sw, scg, pv);
    }

    // tail: wave rl==3 writes its output row
    if (rl == 3) {
        const int hrow = h0 + 3;
#pragma unroll
        for (int m = 0; m < 2; ++m)
#pragma unroll
            for (int n = 0; n < 2; ++n) {
                const int wc = half * 64 + n * 32 + lm;
#pragma unroll
                for (int rg = 0; rg < 16; ++rg) {
                    int co = m * 32 + (rg & 3) + 8 * (rg >> 2) + 4 * g;
                    out[(((size_t)b * CO + co) * HH + hrow) * WW + wc] =
                        acc[m][n][rg] + aggb[b * CO + co];
                }
            }
    }
}

extern "C" void kernel_launch(void* const* d_in, const int* in_sizes, int n_in,
                              void* d_out, int out_size, void* d_ws, size_t ws_size,
                              hipStream_t stream) {
    const float* x       = (const float*)d_in[0];
    const float* weights = (const float*)d_in[1];
    const float* Wbank   = (const float*)d_in[2];
    const float* bbank   = (const float*)d_in[3];
    float* out = (float*)d_out;

    short* aggw = (short*)d_ws;                          // 1,179,648 B
    float* aggb = (float*)((char*)d_ws + 1179648);       //     4,096 B

    prep_kernel<<<dim3((NB * CO * KDIM) / 256), dim3(256), 0, stream>>>(weights, Wbank, bbank, aggw, aggb);
    conv_kernel<<<dim3(32, NB), dim3(512), 0, stream>>>(x, aggw, aggb, out);
}

// Round 6
// 40.936 us; speedup vs baseline: 8.1267x; 8.1267x over previous
//
#include <hip/hip_runtime.h>
#include <hip/hip_bf16.h>

// Dynamic conv2d: B=16, C_in=64, H=W=128, C_out=64, K=5, ks=3, pad=1.
// R6: streaming GEMM. A (aggregated weights) lives in REGISTERS (36 bf16x8
// per wave = its co-half), x streams through a 4-slot LDS row ring, one
// output row per barrier step. All LDS accesses contiguous (0 conflicts).
// Budget: ~240 VGPR @ 2 waves/SIMD (launch_bounds(512,2)), LDS 66,560 B.

typedef __attribute__((ext_vector_type(8))) __bf16 bf16x8;
typedef __attribute__((ext_vector_type(16))) float f32x16;
typedef __attribute__((ext_vector_type(4))) unsigned int u32x4;

#define NB 16
#define CI 64
#define CO 64
#define HH 128
#define WW 128
#define KBANK 5
#define ASTR 36864            // shorts of aggw per b: 2m * 36ks * 2g * 32 * 8

__device__ __forceinline__ unsigned short f2bfu(float f) {
    __hip_bfloat16 h = __float2bfloat16(f);
    unsigned short s;
    __builtin_memcpy(&s, &h, 2);
    return s;
}

// ---------------- kernel 1: aggregate weights + bias ----------------
// aggw layout per b: [m(2)][kstep(36)][g(2)][co5(32)][j(8)] so a wave's
// A-fragment load (lane l) is base + kstep*512 + l*8 -> contiguous 1KB.
// element (b,co,k): co = m*32+co5, k = kstep*16 + g*8 + j, tap=k>>6, ci=k&63.
__global__ void prep_kernel(const float* __restrict__ weights,
                            const float* __restrict__ Wbank,
                            const float* __restrict__ bbank,
                            short* __restrict__ aggw,
                            float* __restrict__ aggb) {
    int idx = blockIdx.x * 256 + threadIdx.x;          // < 16*36864 = 589824
    int b   = idx / ASTR;
    int rem = idx - b * ASTR;
    int j   = rem & 7;
    int co5 = (rem >> 3) & 31;
    int g   = (rem >> 8) & 1;
    int mk  = rem >> 9;                // 0..71 = m*36 + kstep
    int m   = mk / 36;
    int ks  = mk - m * 36;
    int co  = m * 32 + co5;
    int k   = ks * 16 + g * 8 + j;
    int tap = k >> 6;                  // dy*3+dx
    int ci  = k & 63;
    float s = 0.f;
#pragma unroll
    for (int kk = 0; kk < KBANK; ++kk)
        s += weights[b * KBANK + kk] * Wbank[((kk * CO + co) * CI + ci) * 9 + tap];
    aggw[idx] = (short)f2bfu(s);
    if (k == 0) {
        float sb = 0.f;
#pragma unroll
        for (int kk = 0; kk < KBANK; ++kk)
            sb += weights[b * KBANK + kk] * bbank[kk * CO + co];
        aggb[b * CO + co] = sb;
    }
}

// ---------------- kernel 2: streaming conv ----------------
// ring[slot 4][chunk 8][pix 130][8 shorts]; chunk = ci>>3; pix p = input w+1.
__device__ __forceinline__ void load16(const float* __restrict__ xb, int r,
                                       int sw, int scg, float pv[16]) {
#pragma unroll
    for (int i = 0; i < 16; ++i)
        pv[i] = xb[((size_t)(scg * 16 + i) * HH + r) * WW + sw];
}

__device__ __forceinline__ void write16(short* __restrict__ slot, int sw, int scg,
                                        const float pv[16]) {
#pragma unroll
    for (int h = 0; h < 2; ++h) {
        unsigned u0 = (unsigned)f2bfu(pv[h * 8 + 0]) | ((unsigned)f2bfu(pv[h * 8 + 1]) << 16);
        unsigned u1 = (unsigned)f2bfu(pv[h * 8 + 2]) | ((unsigned)f2bfu(pv[h * 8 + 3]) << 16);
        unsigned u2 = (unsigned)f2bfu(pv[h * 8 + 4]) | ((unsigned)f2bfu(pv[h * 8 + 5]) << 16);
        unsigned u3 = (unsigned)f2bfu(pv[h * 8 + 6]) | ((unsigned)f2bfu(pv[h * 8 + 7]) << 16);
        *(u32x4*)&slot[((scg * 2 + h) * 130 + sw + 1) * 8] = u32x4{u0, u1, u2, u3};
    }
}

__global__ __launch_bounds__(512, 2) void conv_kernel(const float* __restrict__ x,
                                                      const short* __restrict__ aggw,
                                                      const float* __restrict__ aggb,
                                                      float* __restrict__ out) {
    __shared__ short ring[4][8][130][8];               // 66,560 B

    const int t   = threadIdx.x;
    const int lin = blockIdx.x;                        // 256 blocks
    const int b     = (lin & 7) * 2 + ((lin >> 3) & 1);// same-b blocks share an XCD
    const int strip = lin >> 4;                        // 0..15
    const int r0    = strip * 8;

    const int l  = t & 63;
    const int wv = t >> 6;         // 0..7
    const int m  = wv >> 2;        // co half
    const int nq = wv & 3;         // pix quarter
    const int lm = l & 31;
    const int g  = l >> 5;

    const int sw  = t & 127;       // staging: w
    const int scg = t >> 7;        // staging: 16-ci group

    const float* xb = x + (size_t)b * CI * HH * WW;
    const short* Ab = aggw + (size_t)b * ASTR + (size_t)m * 36 * 512;

    // ---- A-half into registers: 36 x bf16x8 (144 VGPR), coalesced 1KB/wave
    bf16x8 A[36];
#pragma unroll
    for (int ks = 0; ks < 36; ++ks)
        A[ks] = *(const bf16x8*)(Ab + ks * 512 + l * 8);

    // ---- bias into registers
    float bias[16];
#pragma unroll
    for (int rg = 0; rg < 16; ++rg)
        bias[rg] = aggb[b * CO + m * 32 + (rg & 3) + 8 * (rg >> 2) + 4 * g];

    // ---- zero pix-halo (pix 0 and 129) of all 4 slots
    if (t < 64) {
        int slot = t >> 4, ch = (t >> 1) & 7, px = (t & 1) * 129;
        *(u32x4*)&ring[slot][ch][px][0] = u32x4{0u, 0u, 0u, 0u};
    }

    // ---- prologue: rows r0-1, r0, r0+1 -> slots 0,1,2 (all loads in flight together)
    {
        float pv0[16] = {0,0,0,0,0,0,0,0,0,0,0,0,0,0,0,0};
        float pv1[16], pv2[16];
        if (r0 >= 1) load16(xb, r0 - 1, sw, scg, pv0);
        load16(xb, r0,     sw, scg, pv1);
        load16(xb, r0 + 1, sw, scg, pv2);
        write16(&ring[0][0][0][0], sw, scg, pv0);
        write16(&ring[1][0][0][0], sw, scg, pv1);
        write16(&ring[2][0][0][0], sw, scg, pv2);
    }
    __syncthreads();

    // ---- 8 row-steps
    for (int ri = 0; ri < 8; ++ri) {
        const int r = r0 + ri;

        // issue next x-row loads at step START (one full step of latency cover)
        float pv[16] = {0,0,0,0,0,0,0,0,0,0,0,0,0,0,0,0};
        const bool stage = (ri < 7);
        if (stage && (r + 2 < 128)) load16(xb, r + 2, sw, scg, pv);

        const short* s0 = &ring[(ri    ) & 3][0][0][0];
        const short* s1 = &ring[(ri + 1) & 3][0][0][0];
        const short* s2 = &ring[(ri + 2) & 3][0][0][0];

        f32x16 acc = (f32x16)0.0f;
#pragma unroll
        for (int ks = 0; ks < 36; ++ks) {
            const int tap = ks >> 2, q = ks & 3;
            const int dy = tap / 3, dx = tap - dy * 3;
            const short* sb = (dy == 0) ? s0 : (dy == 1) ? s1 : s2;
            const int pix = nq * 32 + dx + lm;         // ring pix = w_in + 1
            bf16x8 bv = *(const bf16x8*)&sb[((q * 2 + g) * 130 + pix) * 8];
            acc = __builtin_amdgcn_mfma_f32_32x32x16_bf16(A[ks], bv, acc, 0, 0, 0);
        }

        // out stores (fire-and-forget)
        const int wc = nq * 32 + lm;
#pragma unroll
        for (int rg = 0; rg < 16; ++rg) {
            int co = m * 32 + (rg & 3) + 8 * (rg >> 2) + 4 * g;
            out[(((size_t)b * CO + co) * HH + r) * WW + wc] = acc[rg] + bias[rg];
        }

        if (stage) write16((short*)&ring[(ri + 3) & 3][0][0][0], sw, scg, pv);
        __syncthreads();
    }
}

extern "C" void kernel_launch(void* const* d_in, const int* in_sizes, int n_in,
                              void* d_out, int out_size, void* d_ws, size_t ws_size,
                              hipStream_t stream) {
    const float* x       = (const float*)d_in[0];
    const float* weights = (const float*)d_in[1];
    const float* Wbank   = (const float*)d_in[2];
    const float* bbank   = (const float*)d_in[3];
    float* out = (float*)d_out;

    short* aggw = (short*)d_ws;                          // 1,179,648 B
    float* aggb = (float*)((char*)d_ws + 1179648);       //     4,096 B

    prep_kernel<<<dim3((NB * ASTR) / 256), dim3(256), 0, stream>>>(weights, Wbank, bbank, aggw, aggb);
    conv_kernel<<<dim3(256), dim3(512), 0, stream>>>(x, aggw, aggb, out);
}